// Round 6
// baseline (16.095 us; speedup 1.0000x reference)
//
#include <hip/hip_runtime.h>
#include <math.h>

#define NB     2048
#define FEAT   10
#define IN_DIM 7
#define HID    64
#define TAU    22
#define ALPHA  0.2f

// DPP permuted-value fetch (VALU pipe, no LDS). bound_ctrl=1 -> invalid src = 0.
// CTRL must be an integer constant expression -> template parameter.
template <int CTRL>
__device__ __forceinline__ float dpp_mv(float x) {
    return __int_as_float(__builtin_amdgcn_update_dpp(
        0, __float_as_int(x), CTRL, 0xf, 0xf, true));
}

// Full-wave (64) sum, result broadcast to all lanes. rocPRIM DPP sequence:
// xor1, xor2 (quad_perm), row_half_mirror, row_mirror,
// then row_bcast15 + row_bcast31 accumulate the full sum into lane 63;
// readlane broadcasts via SGPR. All VALU-pipe ops -- zero DS-pipe pressure.
__device__ __forceinline__ float wave_sum64(float v) {
    v += dpp_mv<0xB1>(v);    // quad_perm [1,0,3,2]  : xor 1
    v += dpp_mv<0x4E>(v);    // quad_perm [2,3,0,1]  : xor 2
    v += dpp_mv<0x141>(v);   // row_half_mirror      : xor within 8
    v += dpp_mv<0x140>(v);   // row_mirror           : xor within 16
    v += dpp_mv<0x142>(v);   // row_bcast15          : rows 1,3 += prev row end
    v += dpp_mv<0x143>(v);   // row_bcast31          : lanes 32-63 += lane 31
    return __int_as_float(__builtin_amdgcn_readlane(__float_as_int(v), 63));
}

// Single fused kernel. One WAVE per (item, half); 4 waves/block -> 2 items.
// Star-graph GAT collapse (verified R1-R4):
//   att  = softmax_{m=1..127}( leakyrelu( x0.sv1 + x[m].sv2 ) )   [no max-sub:
//          |logit| <~ 1.5 given weight scale 0.1 -- verified R4, absmax 0.008]
//   vvec = elu(x0@W1) + 127*elu((att^T x)@W1)
//   out  = clip(relu( (vv_u@W2u + vv_d@W2d)@fcW + b ), 0, 10)
// Layer-2 attention params (u_out_a/d_out_a) are mathematically unused.
// DS-pipe budget per wave: ~34 ops (was ~140 in R4); 1 block barrier (was 2).
__global__ __launch_bounds__(256) void gat_star_one(
    const float* __restrict__ fp,
    const float* __restrict__ uW1, const float* __restrict__ uA1,
    const float* __restrict__ uW2,
    const float* __restrict__ dW1, const float* __restrict__ dA1,
    const float* __restrict__ dW2,
    const float* __restrict__ fcW, const float* __restrict__ fcB,
    float* __restrict__ out)
{
    __shared__ float svs[4][16];        // per-wave sv1[0..6] @0, sv2[0..6] @8
    __shared__ float vvs[4][HID];       // per-wave vvec
    __shared__ float pts[4][HID];       // per-wave partial tot
    __shared__ float rrs[4][TAU];       // per-wave fc2 projection

    const int tid  = threadIdx.x;
    const int wave = tid >> 6;
    const int lane = tid & 63;
    const int it   = wave >> 1;          // item within block (0/1)
    const int half = wave & 1;           // 0=u, 1=d
    const int item = blockIdx.x * 2 + it;

    // ---- issue fp loads early (hide HBM latency under sv serial work) ----
    const float* xbase = fp + (size_t)item * 256 * FEAT + half * 128 * FEAT;
    const float* pAp = xbase + lane * FEAT;
    const float* pBp = pAp + 64 * FEAT;
    const float2 a0 = *(const float2*)(pAp + 0);
    const float2 a1 = *(const float2*)(pAp + 2);
    const float2 a2 = *(const float2*)(pAp + 4);
    const float  a6 = pAp[6];
    const float2 b0 = *(const float2*)(pBp + 0);
    const float2 b1 = *(const float2*)(pBp + 2);
    const float2 b2 = *(const float2*)(pBp + 4);
    const float  b6 = pBp[6];
    // node-0 features: uniform address (16B-aligned), no shuffles needed
    const float4 x03 = *(const float4*)xbase;
    const float2 x45 = *(const float2*)(xbase + 4);
    const float  x6  = xbase[6];

    const float* W1 = half ? dW1 : uW1;
    const float* A1 = half ? dA1 : uA1;
    float w1c[IN_DIM];
    #pragma unroll
    for (int f = 0; f < IN_DIM; ++f) w1c[f] = W1[f * HID + lane];

    // ---- batch-invariant sv = W1@a: serial on 14 lanes, wave-local LDS bcast ----
    if (lane < 14) {
        const int sp = (lane >= IN_DIM) ? 1 : 0;
        const int f  = lane - sp * IN_DIM;
        const float* wr = W1 + f * HID;
        const float* av = A1 + sp * HID;
        float s0 = 0.f, s1 = 0.f, s2 = 0.f, s3 = 0.f;
        #pragma unroll
        for (int k = 0; k < HID; k += 4) {
            s0 = fmaf(wr[k + 0], av[k + 0], s0);
            s1 = fmaf(wr[k + 1], av[k + 1], s1);
            s2 = fmaf(wr[k + 2], av[k + 2], s2);
            s3 = fmaf(wr[k + 3], av[k + 3], s3);
        }
        svs[wave][sp * 8 + f] = (s0 + s1) + (s2 + s3);
    }
    __builtin_amdgcn_wave_barrier();     // wave-local LDS write->read ordering

    float x0[IN_DIM], xA[IN_DIM], xB[IN_DIM];
    x0[0] = x03.x; x0[1] = x03.y; x0[2] = x03.z; x0[3] = x03.w;
    x0[4] = x45.x; x0[5] = x45.y; x0[6] = x6;
    xA[0] = a0.x; xA[1] = a0.y; xA[2] = a1.x; xA[3] = a1.y;
    xA[4] = a2.x; xA[5] = a2.y; xA[6] = a6;
    xB[0] = b0.x; xB[1] = b0.y; xB[2] = b1.x; xB[3] = b1.y;
    xB[4] = b2.x; xB[5] = b2.y; xB[6] = b6;

    float sv1[IN_DIM], sv2[IN_DIM];
    #pragma unroll
    for (int f = 0; f < IN_DIM; ++f) {
        sv1[f] = svs[wave][f];
        sv2[f] = svs[wave][8 + f];
    }

    // ---- logits e[m] = leakyrelu(x0.sv1 + x[m].sv2) ----
    float s1 = 0.f, sA = 0.f, sB = 0.f;
    #pragma unroll
    for (int f = 0; f < IN_DIM; ++f) {
        s1 = fmaf(x0[f], sv1[f], s1);
        sA = fmaf(xA[f], sv2[f], sA);
        sB = fmaf(xB[f], sv2[f], sB);
    }
    float eA = s1 + sA; eA = (eA >= 0.f) ? eA : ALPHA * eA;
    float eB = s1 + sB; eB = (eB >= 0.f) ? eB : ALPHA * eB;

    // ---- p = exp(e) (node 0 excluded); 8 DPP wave-sums (VALU pipe) ----
    const float qA = (lane == 0) ? 0.f : __expf(eA);
    const float qB = __expf(eB);
    float c[8];
    #pragma unroll
    for (int f = 0; f < IN_DIM; ++f)
        c[f] = wave_sum64(fmaf(qA, xA[f], qB * xB[f]));
    c[7] = wave_sum64(qA + qB);
    const float inv = 1.0f / c[7];

    // ---- lane k: vvec[k] = elu(x0@W1)[k] + 127*elu(xa@W1)[k] ----
    float h0 = 0.f, h1 = 0.f;
    #pragma unroll
    for (int f = 0; f < IN_DIM; ++f) {
        h0 = fmaf(c[f],  w1c[f], h0);
        h1 = fmaf(x0[f], w1c[f], h1);
    }
    h0 *= inv;
    h0 = (h0 > 0.f) ? h0 : (__expf(h0) - 1.f);
    h1 = (h1 > 0.f) ? h1 : (__expf(h1) - 1.f);
    vvs[wave][lane] = h1 + 127.f * h0;
    __builtin_amdgcn_wave_barrier();     // wave-local: no block barrier needed

    // ---- pt[j] = sum_k vv[k]*W2[k][j]  (wave-local; 4 accumulators) ----
    {
        const float* W2 = half ? dW2 : uW2;
        const float* v  = vvs[wave];
        float t0 = 0.f, t1 = 0.f, t2 = 0.f, t3 = 0.f;
        #pragma unroll
        for (int k = 0; k < HID; k += 4) {
            t0 = fmaf(v[k + 0], W2[(k + 0) * HID + lane], t0);
            t1 = fmaf(v[k + 1], W2[(k + 1) * HID + lane], t1);
            t2 = fmaf(v[k + 2], W2[(k + 2) * HID + lane], t2);
            t3 = fmaf(v[k + 3], W2[(k + 3) * HID + lane], t3);
        }
        pts[wave][lane] = (t0 + t1) + (t2 + t3);
    }
    __builtin_amdgcn_wave_barrier();

    // ---- per-wave fc2 projection: r[t] = sum_j pt[j]*fcW[j][t] ----
    // lanes {t, t+32} split j into [0,32) / [32,64); one xor-32 combine
    {
        const float* p = pts[wave];
        int t = lane & 31; if (t > TAU - 1) t = TAU - 1;   // clamp: no OOB
        const int jb = lane & 32;
        float s0 = 0.f, s1_ = 0.f;
        #pragma unroll
        for (int jj = 0; jj < 32; jj += 2) {
            s0  = fmaf(p[jb + jj],     fcW[(jb + jj)     * TAU + t], s0);
            s1_ = fmaf(p[jb + jj + 1], fcW[(jb + jj + 1) * TAU + t], s1_);
        }
        float s = s0 + s1_;
        s += __shfl_xor(s, 32);
        if (lane < TAU) rrs[wave][lane] = s;
    }
    __syncthreads();                     // the ONLY block barrier

    // ---- combine u+d, bias, relu, clip, store ----
    if (half == 0 && lane < TAU) {
        float s = rrs[wave][lane] + rrs[wave + 1][lane] + fcB[lane];
        s = fminf(fmaxf(s, 0.f), 10.f);
        out[(size_t)item * TAU + lane] = s;
    }
}

extern "C" void kernel_launch(void* const* d_in, const int* in_sizes, int n_in,
                              void* d_out, int out_size, void* d_ws, size_t ws_size,
                              hipStream_t stream) {
    const float* fp  = (const float*)d_in[0];
    const float* uW1 = (const float*)d_in[1];
    const float* uA1 = (const float*)d_in[2];
    const float* uW2 = (const float*)d_in[3];
    // d_in[4] = u_out_a : mathematically unused (uniform layer-2 softmax)
    const float* dW1 = (const float*)d_in[5];
    const float* dA1 = (const float*)d_in[6];
    const float* dW2 = (const float*)d_in[7];
    // d_in[8] = d_out_a : unused
    const float* fcW = (const float*)d_in[9];
    const float* fcB = (const float*)d_in[10];
    float* out = (float*)d_out;

    gat_star_one<<<NB / 2, 256, 0, stream>>>(fp, uW1, uA1, uW2,
                                             dW1, dA1, dW2, fcW, fcB, out);
}

// Round 7
// 14.260 us; speedup vs baseline: 1.1287x; 1.1287x over previous
//
#include <hip/hip_runtime.h>
#include <math.h>

#define NB     2048
#define FEAT   10
#define IN_DIM 7
#define HID    64
#define TAU    22
#define ALPHA  0.2f

// DPP permuted-value fetch (VALU pipe, no LDS). bound_ctrl=1 -> invalid src = 0.
template <int CTRL>
__device__ __forceinline__ float dpp_mv(float x) {
    return __int_as_float(__builtin_amdgcn_update_dpp(
        0, __float_as_int(x), CTRL, 0xf, 0xf, true));
}

// 16-lane (row) sum: after 4 stages every lane of the row holds the row sum.
// xor1, xor2 via quad_perm; half_mirror (=xor7, valid after quads equal);
// row_mirror (=xor15, valid after halves equal). All VALU.
__device__ __forceinline__ float row_sum16(float v) {
    v += dpp_mv<0xB1>(v);    // quad_perm [1,0,3,2]
    v += dpp_mv<0x4E>(v);    // quad_perm [2,3,0,1]
    v += dpp_mv<0x141>(v);   // row_half_mirror
    v += dpp_mv<0x140>(v);   // row_mirror
    return v;
}

// Full 64-lane sum broadcast to all lanes (verified R6: correct results).
__device__ __forceinline__ float wave_sum64(float v) {
    v = row_sum16(v);
    v += dpp_mv<0x142>(v);   // row_bcast15
    v += dpp_mv<0x143>(v);   // row_bcast31  -> lanes 48-63 hold full sum
    return __int_as_float(__builtin_amdgcn_readlane(__float_as_int(v), 63));
}

// One WAVE per (item, half); 4 waves/block -> 2 items/block.
// Star-graph GAT collapse (verified R1-R6):
//   att  = softmax_{m=1..127}( leakyrelu( x0.sv1 + x[m].sv2 ) )  [no max-sub:
//          |logit| <~ 1.5 at weight scale 0.1 -- verified, absmax 0.008]
//   vvec = elu(x0@W1) + 127*elu((att^T x)@W1)
//   out  = clip(relu( (vv_u@W2u + vv_d@W2d)@fcW + b ), 0, 10)
// u_out_a/d_out_a mathematically unused (uniform layer-2 softmax).
// R7: all reductions on VALU (DPP); DS ops/wave ~28 (R4: ~240).
__global__ __launch_bounds__(256) void gat_star_one(
    const float* __restrict__ fp,
    const float* __restrict__ uW1, const float* __restrict__ uA1,
    const float* __restrict__ uW2,
    const float* __restrict__ dW1, const float* __restrict__ dA1,
    const float* __restrict__ dW2,
    const float* __restrict__ fcW, const float* __restrict__ fcB,
    float* __restrict__ out)
{
    __shared__ float vvs[4][HID];       // per-wave vvec (lane k -> [k])
    __shared__ float rrs[4][TAU];       // per-wave fc2 projection

    const int tid  = threadIdx.x;
    const int wave = tid >> 6;
    const int lane = tid & 63;
    const int it   = wave >> 1;          // item within block (0/1)
    const int half = wave & 1;           // 0=u, 1=d
    const int item = blockIdx.x * 2 + it;

    // ---- issue fp loads early ----
    const float* xbase = fp + (size_t)item * 256 * FEAT + half * 128 * FEAT;
    const float* pAp = xbase + lane * FEAT;
    const float* pBp = pAp + 64 * FEAT;
    const float2 a0 = *(const float2*)(pAp + 0);
    const float2 a1 = *(const float2*)(pAp + 2);
    const float2 a2 = *(const float2*)(pAp + 4);
    const float  a6 = pAp[6];
    const float2 b0 = *(const float2*)(pBp + 0);
    const float2 b1 = *(const float2*)(pBp + 2);
    const float2 b2 = *(const float2*)(pBp + 4);
    const float  b6 = pBp[6];
    // node-0 features: uniform address, L1 broadcast (no shuffles)
    const float4 x03 = *(const float4*)xbase;
    const float2 x45 = *(const float2*)(xbase + 4);
    const float  x6  = xbase[6];

    const float* W1 = half ? dW1 : uW1;
    const float* A1 = half ? dA1 : uA1;
    float w1c[IN_DIM];
    #pragma unroll
    for (int f = 0; f < IN_DIM; ++f) w1c[f] = W1[f * HID + lane];
    const float alo = A1[lane];
    const float ahi = A1[HID + lane];

    // ---- batch-invariant sv = W1@a via 14 DPP wave-sums (register data) ----
    float sv1[IN_DIM], sv2[IN_DIM];
    #pragma unroll
    for (int f = 0; f < IN_DIM; ++f) {
        sv1[f] = wave_sum64(w1c[f] * alo);
        sv2[f] = wave_sum64(w1c[f] * ahi);
    }

    float x0[IN_DIM], xA[IN_DIM], xB[IN_DIM];
    x0[0] = x03.x; x0[1] = x03.y; x0[2] = x03.z; x0[3] = x03.w;
    x0[4] = x45.x; x0[5] = x45.y; x0[6] = x6;
    xA[0] = a0.x; xA[1] = a0.y; xA[2] = a1.x; xA[3] = a1.y;
    xA[4] = a2.x; xA[5] = a2.y; xA[6] = a6;
    xB[0] = b0.x; xB[1] = b0.y; xB[2] = b1.x; xB[3] = b1.y;
    xB[4] = b2.x; xB[5] = b2.y; xB[6] = b6;

    // ---- logits e[m] = leakyrelu(x0.sv1 + x[m].sv2) ----
    float s1 = 0.f, sA = 0.f, sB = 0.f;
    #pragma unroll
    for (int f = 0; f < IN_DIM; ++f) {
        s1 = fmaf(x0[f], sv1[f], s1);
        sA = fmaf(xA[f], sv2[f], sA);
        sB = fmaf(xB[f], sv2[f], sB);
    }
    float eA = s1 + sA; eA = (eA >= 0.f) ? eA : ALPHA * eA;
    float eB = s1 + sB; eB = (eB >= 0.f) ? eB : ALPHA * eB;

    // ---- p = exp(e) (node 0 excluded); 8 DPP wave-sums ----
    const float qA = (lane == 0) ? 0.f : __expf(eA);
    const float qB = __expf(eB);
    float c[8];
    #pragma unroll
    for (int f = 0; f < IN_DIM; ++f)
        c[f] = wave_sum64(fmaf(qA, xA[f], qB * xB[f]));
    c[7] = wave_sum64(qA + qB);
    const float inv = 1.0f / c[7];

    // ---- lane k: vvec[k] = elu(x0@W1)[k] + 127*elu(xa@W1)[k] ----
    float h0 = 0.f, h1 = 0.f;
    #pragma unroll
    for (int f = 0; f < IN_DIM; ++f) {
        h0 = fmaf(c[f],  w1c[f], h0);
        h1 = fmaf(x0[f], w1c[f], h1);
    }
    h0 *= inv;
    h0 = (h0 > 0.f) ? h0 : (__expf(h0) - 1.f);
    h1 = (h1 > 0.f) ? h1 : (__expf(h1) - 1.f);
    vvs[wave][lane] = h1 + 127.f * h0;
    __builtin_amdgcn_wave_barrier();     // wave-local LDS write->read ordering

    // ---- W2 matvec, split-k: lane=(kc,jg); pt[4jg+i] = sum_k vv[k]W2[k][4jg+i]
    const int jg = lane & 15;            // j-group (4 outputs)
    const int kc = lane >> 4;            // k-chunk of 16
    const float* W2 = half ? dW2 : uW2;
    float t0 = 0.f, t1 = 0.f, t2 = 0.f, t3 = 0.f;
    #pragma unroll
    for (int kk = 0; kk < 16; ++kk) {
        const int k = kc * 16 + kk;
        const float vvk = vvs[wave][k];                       // LDS bcast read
        const float4 w = *(const float4*)(W2 + k * HID + jg * 4);
        t0 = fmaf(vvk, w.x, t0);
        t1 = fmaf(vvk, w.y, t1);
        t2 = fmaf(vvk, w.z, t2);
        t3 = fmaf(vvk, w.w, t3);
    }
    // combine the 4 k-chunks: every lane ends with final pt[4jg+i]
    t0 += __shfl_xor(t0, 16); t0 += __shfl_xor(t0, 32);
    t1 += __shfl_xor(t1, 16); t1 += __shfl_xor(t1, 32);
    t2 += __shfl_xor(t2, 16); t2 += __shfl_xor(t2, 32);
    t3 += __shfl_xor(t3, 16); t3 += __shfl_xor(t3, 32);

    // ---- fc2: row kc handles t = 6*kc .. 6*kc+5 (row 3: 4 t's).
    // lane contributes its 4 j's; 4-stage in-row DPP reduce per t.
    const int tbase = kc * 6;
    const int j4 = jg * 4;
    float fs0 = 0.f, fs1 = 0.f, fs2 = 0.f, fs3 = 0.f, fs4 = 0.f, fs5 = 0.f;
#define FC2_T(TT, DST)                                                        \
    { const int t_ = tbase + (TT);                                            \
      if (t_ < TAU) {                                                         \
          float a_ = t0 * fcW[(j4 + 0) * TAU + t_];                           \
          a_ = fmaf(t1, fcW[(j4 + 1) * TAU + t_], a_);                        \
          a_ = fmaf(t2, fcW[(j4 + 2) * TAU + t_], a_);                        \
          a_ = fmaf(t3, fcW[(j4 + 3) * TAU + t_], a_);                        \
          DST = row_sum16(a_);                                                \
      } }
    FC2_T(0, fs0) FC2_T(1, fs1) FC2_T(2, fs2)
    FC2_T(3, fs3) FC2_T(4, fs4) FC2_T(5, fs5)
#undef FC2_T
    if (jg < 6) {
        const int t_ = tbase + jg;
        if (t_ < TAU) {
            float v_ = (jg == 0) ? fs0 : (jg == 1) ? fs1 : (jg == 2) ? fs2
                     : (jg == 3) ? fs3 : (jg == 4) ? fs4 : fs5;
            rrs[wave][t_] = v_;
        }
    }
    __syncthreads();                     // the ONLY block barrier

    // ---- combine u+d, bias, relu, clip, store ----
    if (half == 0 && lane < TAU) {
        float s = rrs[wave][lane] + rrs[wave + 1][lane] + fcB[lane];
        s = fminf(fmaxf(s, 0.f), 10.f);
        out[(size_t)item * TAU + lane] = s;
    }
}

extern "C" void kernel_launch(void* const* d_in, const int* in_sizes, int n_in,
                              void* d_out, int out_size, void* d_ws, size_t ws_size,
                              hipStream_t stream) {
    const float* fp  = (const float*)d_in[0];
    const float* uW1 = (const float*)d_in[1];
    const float* uA1 = (const float*)d_in[2];
    const float* uW2 = (const float*)d_in[3];
    // d_in[4] = u_out_a : mathematically unused (uniform layer-2 softmax)
    const float* dW1 = (const float*)d_in[5];
    const float* dA1 = (const float*)d_in[6];
    const float* dW2 = (const float*)d_in[7];
    // d_in[8] = d_out_a : unused
    const float* fcW = (const float*)d_in[9];
    const float* fcB = (const float*)d_in[10];
    float* out = (float*)d_out;

    gat_star_one<<<NB / 2, 256, 0, stream>>>(fp, uW1, uA1, uW2,
                                             dW1, dA1, dW2, fcW, fcB, out);
}

// Round 8
// 14.088 us; speedup vs baseline: 1.1424x; 1.0122x over previous
//
#include <hip/hip_runtime.h>
#include <math.h>

#define NB     2048
#define FEAT   10
#define IN_DIM 7
#define HID    64
#define TAU    22
#define ALPHA  0.2f

// DPP permuted-value fetch (VALU pipe, no LDS). bound_ctrl=1 -> invalid src = 0.
template <int CTRL>
__device__ __forceinline__ float dpp_mv(float x) {
    return __int_as_float(__builtin_amdgcn_update_dpp(
        0, __float_as_int(x), CTRL, 0xf, 0xf, true));
}

// 16-lane (row) sum: after 4 stages every lane of the row holds the row sum.
__device__ __forceinline__ float row_sum16(float v) {
    v += dpp_mv<0xB1>(v);    // quad_perm [1,0,3,2]
    v += dpp_mv<0x4E>(v);    // quad_perm [2,3,0,1]
    v += dpp_mv<0x141>(v);   // row_half_mirror
    v += dpp_mv<0x140>(v);   // row_mirror
    return v;
}

// Full 64-lane sum broadcast to all lanes (verified R6/R7).
__device__ __forceinline__ float wave_sum64(float v) {
    v = row_sum16(v);
    v += dpp_mv<0x142>(v);   // row_bcast15
    v += dpp_mv<0x143>(v);   // row_bcast31 -> lanes 48-63 hold full sum
    return __int_as_float(__builtin_amdgcn_readlane(__float_as_int(v), 63));
}

// One WAVE per (item, half); 4 waves/block -> 2 items/block.
// Star-graph GAT collapse (verified R1-R7, absmax <= 0.016):
//   att  = softmax_{m=1..127}( leakyrelu( s1 + x[m].sv2 ) )   [no max-sub]
//   vvec = elu(x0@W1) + 127*elu((att^T x)@W1)
//   out  = clip(relu( (vv_u@W2u + vv_d@W2d)@fcW + b ), 0, 10)
// R8: lane l owns rows 2l/2l+1 -> fp = 5 coalesced float4/lane (was 8 VMEM);
//     s1 folded to ONE wave-sum via s1 = wave_sum64((x0.w1c)*alo); h1 = d0.
// u_out_a/d_out_a mathematically unused (uniform layer-2 softmax).
__global__ __launch_bounds__(256) void gat_star_one(
    const float* __restrict__ fp,
    const float* __restrict__ uW1, const float* __restrict__ uA1,
    const float* __restrict__ uW2,
    const float* __restrict__ dW1, const float* __restrict__ dA1,
    const float* __restrict__ dW2,
    const float* __restrict__ fcW, const float* __restrict__ fcB,
    float* __restrict__ out)
{
    __shared__ float vvs[4][HID];       // per-wave vvec (lane k -> [k])
    __shared__ float rrs[4][TAU];       // per-wave fc2 projection

    const int tid  = threadIdx.x;
    const int wave = tid >> 6;
    const int lane = tid & 63;
    const int it   = wave >> 1;          // item within block (0/1)
    const int half = wave & 1;           // 0=u, 1=d
    const int item = blockIdx.x * 2 + it;

    // ---- fp stream: lane owns rows 2l,2l+1 = 80 B = 5 aligned float4 ----
    const float* xbase = fp + (size_t)item * 256 * FEAT + half * 128 * FEAT;
    const float4* vsrc = (const float4*)xbase;   // 5120-float offset: 16B aligned
    const float4 v0 = vsrc[lane * 5 + 0];
    const float4 v1 = vsrc[lane * 5 + 1];
    const float4 v2 = vsrc[lane * 5 + 2];
    const float4 v3 = vsrc[lane * 5 + 3];
    const float4 v4 = vsrc[lane * 5 + 4];
    // node-0 features (uniform address, L1 broadcast): feats 0-6
    const float4 xq0 = *(const float4*)xbase;
    const float4 xq1 = *(const float4*)(xbase + 4);

    const float* W1 = half ? dW1 : uW1;
    const float* A1 = half ? dA1 : uA1;
    float w1c[IN_DIM];
    #pragma unroll
    for (int f = 0; f < IN_DIM; ++f) w1c[f] = W1[f * HID + lane];
    const float alo = A1[lane];
    const float ahi = A1[HID + lane];

    float x0[IN_DIM];
    x0[0] = xq0.x; x0[1] = xq0.y; x0[2] = xq0.z; x0[3] = xq0.w;
    x0[4] = xq1.x; x0[5] = xq1.y; x0[6] = xq1.z;

    // ---- d0 = x0 . w1c  (this is also h1 = (x0@W1)[lane]) ----
    float d0 = 0.f;
    #pragma unroll
    for (int f = 0; f < IN_DIM; ++f) d0 = fmaf(x0[f], w1c[f], d0);

    // ---- batch-invariant: s1 = x0.(W1@a_lo) in ONE wave-sum; sv2 in 7 ----
    const float s1 = wave_sum64(d0 * alo);
    float sv2[IN_DIM];
    #pragma unroll
    for (int f = 0; f < IN_DIM; ++f) sv2[f] = wave_sum64(w1c[f] * ahi);

    // ---- my two rows' features: A=row 2l (floats 0-6), B=row 2l+1 (10-16) ----
    float xA[IN_DIM], xB[IN_DIM];
    xA[0] = v0.x; xA[1] = v0.y; xA[2] = v0.z; xA[3] = v0.w;
    xA[4] = v1.x; xA[5] = v1.y; xA[6] = v1.z;
    xB[0] = v2.z; xB[1] = v2.w; xB[2] = v3.x; xB[3] = v3.y;
    xB[4] = v3.z; xB[5] = v3.w; xB[6] = v4.x;

    // ---- logits ----
    float sA = 0.f, sB = 0.f;
    #pragma unroll
    for (int f = 0; f < IN_DIM; ++f) {
        sA = fmaf(xA[f], sv2[f], sA);
        sB = fmaf(xB[f], sv2[f], sB);
    }
    float eA = s1 + sA; eA = (eA >= 0.f) ? eA : ALPHA * eA;
    float eB = s1 + sB; eB = (eB >= 0.f) ? eB : ALPHA * eB;

    // ---- p = exp(e) (node 0 = lane 0 slot A excluded); 8 wave-sums ----
    const float qA = (lane == 0) ? 0.f : __expf(eA);
    const float qB = __expf(eB);
    float c[8];
    #pragma unroll
    for (int f = 0; f < IN_DIM; ++f)
        c[f] = wave_sum64(fmaf(qA, xA[f], qB * xB[f]));
    c[7] = wave_sum64(qA + qB);
    const float inv = 1.0f / c[7];

    // ---- lane k: vvec[k] = elu(d0) + 127*elu((c.w1c)*inv) ----
    float h0 = 0.f;
    #pragma unroll
    for (int f = 0; f < IN_DIM; ++f) h0 = fmaf(c[f], w1c[f], h0);
    h0 *= inv;
    h0 = (h0 > 0.f) ? h0 : (__expf(h0) - 1.f);
    float h1 = d0;
    h1 = (h1 > 0.f) ? h1 : (__expf(h1) - 1.f);
    vvs[wave][lane] = h1 + 127.f * h0;
    __builtin_amdgcn_wave_barrier();     // wave-local LDS write->read ordering

    // ---- W2 matvec, split-k: lane=(kc,jg); pt[4jg+i] = sum_k vv[k]W2[k][4jg+i]
    const int jg = lane & 15;            // j-group (4 outputs)
    const int kc = lane >> 4;            // k-chunk of 16
    const float* W2 = half ? dW2 : uW2;
    float t0 = 0.f, t1 = 0.f, t2 = 0.f, t3 = 0.f;
    #pragma unroll
    for (int kk = 0; kk < 16; ++kk) {
        const int k = kc * 16 + kk;
        const float vvk = vvs[wave][k];                       // LDS bcast read
        const float4 w = *(const float4*)(W2 + k * HID + jg * 4);
        t0 = fmaf(vvk, w.x, t0);
        t1 = fmaf(vvk, w.y, t1);
        t2 = fmaf(vvk, w.z, t2);
        t3 = fmaf(vvk, w.w, t3);
    }
    // combine the 4 k-chunks: every lane ends with final pt[4jg+i]
    t0 += __shfl_xor(t0, 16); t0 += __shfl_xor(t0, 32);
    t1 += __shfl_xor(t1, 16); t1 += __shfl_xor(t1, 32);
    t2 += __shfl_xor(t2, 16); t2 += __shfl_xor(t2, 32);
    t3 += __shfl_xor(t3, 16); t3 += __shfl_xor(t3, 32);

    // ---- fc2: row kc handles t = 6*kc .. 6*kc+5 (row 3: 4 t's) ----
    const int tbase = kc * 6;
    const int j4 = jg * 4;
    float fs0 = 0.f, fs1 = 0.f, fs2 = 0.f, fs3 = 0.f, fs4 = 0.f, fs5 = 0.f;
#define FC2_T(TT, DST)                                                        \
    { const int t_ = tbase + (TT);                                            \
      if (t_ < TAU) {                                                         \
          float a_ = t0 * fcW[(j4 + 0) * TAU + t_];                           \
          a_ = fmaf(t1, fcW[(j4 + 1) * TAU + t_], a_);                        \
          a_ = fmaf(t2, fcW[(j4 + 2) * TAU + t_], a_);                        \
          a_ = fmaf(t3, fcW[(j4 + 3) * TAU + t_], a_);                        \
          DST = row_sum16(a_);                                                \
      } }
    FC2_T(0, fs0) FC2_T(1, fs1) FC2_T(2, fs2)
    FC2_T(3, fs3) FC2_T(4, fs4) FC2_T(5, fs5)
#undef FC2_T
    if (jg < 6) {
        const int t_ = tbase + jg;
        if (t_ < TAU) {
            float v_ = (jg == 0) ? fs0 : (jg == 1) ? fs1 : (jg == 2) ? fs2
                     : (jg == 3) ? fs3 : (jg == 4) ? fs4 : fs5;
            rrs[wave][t_] = v_;
        }
    }
    __syncthreads();                     // the ONLY block barrier

    // ---- combine u+d, bias, relu, clip, store ----
    if (half == 0 && lane < TAU) {
        float s = rrs[wave][lane] + rrs[wave + 1][lane] + fcB[lane];
        s = fminf(fmaxf(s, 0.f), 10.f);
        out[(size_t)item * TAU + lane] = s;
    }
}

extern "C" void kernel_launch(void* const* d_in, const int* in_sizes, int n_in,
                              void* d_out, int out_size, void* d_ws, size_t ws_size,
                              hipStream_t stream) {
    const float* fp  = (const float*)d_in[0];
    const float* uW1 = (const float*)d_in[1];
    const float* uA1 = (const float*)d_in[2];
    const float* uW2 = (const float*)d_in[3];
    // d_in[4] = u_out_a : mathematically unused (uniform layer-2 softmax)
    const float* dW1 = (const float*)d_in[5];
    const float* dA1 = (const float*)d_in[6];
    const float* dW2 = (const float*)d_in[7];
    // d_in[8] = d_out_a : unused
    const float* fcW = (const float*)d_in[9];
    const float* fcB = (const float*)d_in[10];
    float* out = (float*)d_out;

    gat_star_one<<<NB / 2, 256, 0, stream>>>(fp, uW1, uA1, uW2,
                                             dW1, dA1, dW2, fcW, fcB, out);
}